// Round 9
// baseline (775.860 us; speedup 1.0000x reference)
//
#include <hip/hip_runtime.h>

// VQ codebook lookup: B=4194304 rows, K=10 codes, D=16 dims, fp32.
// Outputs (concatenated in d_out as fp32): z_q_st (B*D), indices (B, as float),
// commitment_loss (1).
//
// Round 9 (resubmit of round 8): coalesced I/O via in-register 4x4 shuffle
// transpose (4-lane groups). No LDS staging, no barriers in the main loop.
// Phase-1 math verbatim from the round-2 kernel (passed, absmax 0.0).

typedef float f32x4 __attribute__((ext_vector_type(4)));

constexpr long long NB = 4194304LL; // batch
constexpr int KC = 10;              // num codes
constexpr int DD = 16;              // code dim
constexpr int BLK = 256;            // threads per block; chunk = 256 rows
constexpr int CHUNKS = (int)(NB / BLK); // 16384
constexpr int GRID = 2048;          // 8 chunks per block

__global__ void vq_zero_loss(float* p) { *p = 0.0f; }

__global__ __launch_bounds__(BLK, 4) void vq_kernel(
    const float* __restrict__ z_e,
    const float* __restrict__ codebook,
    float* __restrict__ zq_out,
    float* __restrict__ idx_out,
    float* __restrict__ loss_out)
{
    __shared__ float sE[KC * DD]; // codebook rows (64B-aligned rows, broadcast reads)
    __shared__ float sN[KC];      // ||e_k||^2

    const int tid = threadIdx.x;
    if (tid < KC * DD) sE[tid] = codebook[tid];
    __syncthreads();
    if (tid < KC) {
        float n = 0.f;
#pragma unroll
        for (int d = 0; d < DD; ++d) { float v = sE[tid * DD + d]; n += v * v; }
        sN[tid] = n;
    }
    __syncthreads(); // sN/sE visible to all; no further barriers needed

    const int p       = tid & 3;          // quarter index within 4-lane group
    const int grpbase = (tid & 63) & ~3;  // group base lane within this wave

    float loss_acc = 0.f;

    for (int c = blockIdx.x; c < CHUNKS; c += GRID) {
        // ---- coalesced loads: thread holds quarter p of rows j*64+(tid>>2) ----
        const float* gsrc = z_e + (long long)c * (BLK * DD);
        f32x4 ld[4];
#pragma unroll
        for (int j = 0; j < 4; ++j)
            ld[j] = *reinterpret_cast<const f32x4*>(gsrc + (j * BLK + tid) * 4);

        // ---- 4x4 in-register transpose within each 4-lane group ----
        // After this, thread owns FULL row r = p*64 + (tid>>2) in zr[0..15].
        // (element: ld[j][i] of lane grpbase+pp == row j*64+g, col 4*pp+i)
        float zr[DD];
#pragma unroll
        for (int j = 0; j < 4; ++j) {
#pragma unroll
            for (int pp = 0; pp < 4; ++pp) {
#pragma unroll
                for (int i = 0; i < 4; ++i) {
                    const float t = __shfl(ld[j][i], grpbase + pp, 64);
                    if (p == j) zr[pp * 4 + i] = t; // compile-time zr index
                }
            }
        }

        // ---- phase 1: VERBATIM round-2 math (bit-exact, absmax was 0.0) ----
        float sumz = 0.f;
#pragma unroll
        for (int d = 0; d < DD; ++d) sumz += zr[d] * zr[d];

        float best = __builtin_inff();
        int bk = 0;
#pragma unroll
        for (int k = 0; k < KC; ++k) {
            const f32x4* ep = reinterpret_cast<const f32x4*>(sE + k * DD);
            const f32x4 e0 = ep[0], e1 = ep[1], e2 = ep[2], e3 = ep[3];
            float er[DD];
            er[0] = e0[0]; er[1] = e0[1]; er[2]  = e0[2]; er[3]  = e0[3];
            er[4] = e1[0]; er[5] = e1[1]; er[6]  = e1[2]; er[7]  = e1[3];
            er[8] = e2[0]; er[9] = e2[1]; er[10] = e2[2]; er[11] = e2[3];
            er[12] = e3[0]; er[13] = e3[1]; er[14] = e3[2]; er[15] = e3[3];

            float dot = 0.f;
#pragma unroll
            for (int d = 0; d < DD; ++d) dot = fmaf(zr[d], er[d], dot);

            const float dist = (sumz - 2.0f * dot) + sN[k];
            if (dist < best) { best = dist; bk = k; } // first-min, matches argmin
        }

        // loss contribution, same order/expression as round 2
        const f32x4* bp = reinterpret_cast<const f32x4*>(sE + bk * DD);
        const f32x4 q0 = bp[0], q1 = bp[1], q2 = bp[2], q3 = bp[3];
        float qr[DD];
        qr[0] = q0[0]; qr[1] = q0[1]; qr[2]  = q0[2]; qr[3]  = q0[3];
        qr[4] = q1[0]; qr[5] = q1[1]; qr[6]  = q1[2]; qr[7]  = q1[3];
        qr[8] = q2[0]; qr[9] = q2[1]; qr[10] = q2[2]; qr[11] = q2[3];
        qr[12] = q3[0]; qr[13] = q3[1]; qr[14] = q3[2]; qr[15] = q3[3];
#pragma unroll
        for (int d = 0; d < DD; ++d) {
            const float diff = qr[d] - zr[d];
            loss_acc = fmaf(diff, diff, loss_acc);
        }

        // indices: owner of row p*64+(tid>>2) writes it (4B scattered in 64B runs)
        idx_out[(long long)c * BLK + p * 64 + (tid >> 2)] = (float)bk;

        // ---- shuffle row-codes back; store z+(q-z) to the addresses we loaded ----
        int b4[4];
#pragma unroll
        for (int j = 0; j < 4; ++j)
            b4[j] = __shfl(bk, grpbase + j, 64); // code of row j*64+g

        float* gdst = zq_out + (long long)c * (BLK * DD);
#pragma unroll
        for (int j = 0; j < 4; ++j) {
            f32x4 o;
#pragma unroll
            for (int i = 0; i < 4; ++i) {
                const float zv = ld[j][i];                 // z (still in regs)
                const float qv = sE[b4[j] * DD + p * 4 + i];
                o[i] = zv + (qv - zv);                     // same expr as round 2
            }
            *reinterpret_cast<f32x4*>(gdst + (j * BLK + tid) * 4) = o; // coalesced
        }
    }

    // ---- loss reduction: wave(64) shuffle -> block LDS -> one atomic ----
#pragma unroll
    for (int off = 32; off > 0; off >>= 1)
        loss_acc += __shfl_down(loss_acc, off);

    __shared__ float wsum[4];
    const int wave = tid >> 6;
    const int lane = tid & 63;
    if (lane == 0) wsum[wave] = loss_acc;
    __syncthreads();
    if (tid == 0) {
        const float s = (wsum[0] + wsum[1] + wsum[2] + wsum[3]) * (1.0f / 67108864.0f); // 1/(B*D)
        atomicAdd(loss_out, s);
    }
}

extern "C" void kernel_launch(void* const* d_in, const int* in_sizes, int n_in,
                              void* d_out, int out_size, void* d_ws, size_t ws_size,
                              hipStream_t stream) {
    const float* z_e      = (const float*)d_in[0];
    const float* codebook = (const float*)d_in[1];

    float* out      = (float*)d_out;
    float* zq_out   = out;                 // B*D
    float* idx_out  = out + NB * DD;       // B
    float* loss_out = out + NB * DD + NB;  // 1

    vq_zero_loss<<<1, 1, 0, stream>>>(loss_out);
    vq_kernel<<<GRID, BLK, 0, stream>>>(z_e, codebook, zq_out, idx_out, loss_out);
}